// Round 5
// baseline (486.763 us; speedup 1.0000x reference)
//
#include <hip/hip_runtime.h>

// VectorQuantizer, bit-replicating the harness's numpy fp32 reference.
// x [64,64,64,64] f32 -> flat [N=262144, D=64]; emb [D=64, K=512].
// out = concat(quantized_st flat [16777216], loss [1]) as f32.
//
// R5 restructure: thread=CODE (512 threads = 512 codes), not thread=row.
//   - code row e[k][0..63] lives in 16 named float4 VGPRs, loaded once per block
//   - x row address is wave-uniform -> s_load (scalar pipe); FMA = v_fmac v,s,v
//   - per-row argmin across the block: fminf shuffle tree (bit-exact select) +
//     ballot -> lowest lane, then one u64 atomicMin((distbits<<32)|k) per wave.
//     dist>0 always (||z-e||^2 ~ 20..130) so fp32 bits are order-monotonic;
//     u64 min = (dist, k) lexicographic = numpy strict-< first-occurrence.
//   - numerics per (row,k) identical to the PROVEN R2 chain (absmax 0.0):
//     a = sequential fmaf d=0..63; t = fl(z2+e2k); dist = fl(t-2a) (2a exact)
//
// ws layout (bytes):
//   0       : float  et[512*64]     (transposed codebook)      131072
//   131072  : float  e2[512]        (np-order norms)             2048
//   133120  : float  z2[262144]     (np pairwise row norms)   1048576
//   1181696 : u64    gmin[262144]   (packed argmin)           2097152
//   3278848 : double partials[1024] (loss partials)              8192

#define NROWS 262144
#define D 64
#define K 512

#define WS_ET 0
#define WS_E2 131072
#define WS_Z2 133120
#define WS_GMIN 1181696
#define WS_PARTIALS 3278848

// ---- K1: transpose codebook + numpy-order squared norms ----
__global__ void __launch_bounds__(512) vq_prep(const float* __restrict__ emb, char* ws) {
    float* e2 = (float*)(ws + WS_E2);
    float* et = (float*)(ws + WS_ET);
    int k = threadIdx.x;  // 512 threads, one code each
    float v0 = emb[k];
    et[k * D] = v0;
    float s = __fmul_rn(v0, v0);
    for (int d = 1; d < D; ++d) {
        float v = emb[d * K + k];
        et[k * D + d] = v;
        s = __fadd_rn(s, __fmul_rn(v, v));  // sequential over d (np axis-0 reduce)
    }
    e2[k] = s;
}

// ---- K2: per-row z2 (numpy pairwise order) + gmin init ----
__global__ void __launch_bounds__(256) vq_z2(const float* __restrict__ x, char* ws) {
    float* z2 = (float*)(ws + WS_Z2);
    unsigned long long* gmin = (unsigned long long*)(ws + WS_GMIN);
    const int row = blockIdx.x * 256 + threadIdx.x;
    const float4* xr = (const float4*)(x + (size_t)row * D);

    float4 v0 = xr[0], v1 = xr[1];
    float r0 = __fmul_rn(v0.x, v0.x), r1 = __fmul_rn(v0.y, v0.y);
    float r2 = __fmul_rn(v0.z, v0.z), r3 = __fmul_rn(v0.w, v0.w);
    float r4 = __fmul_rn(v1.x, v1.x), r5 = __fmul_rn(v1.y, v1.y);
    float r6 = __fmul_rn(v1.z, v1.z), r7 = __fmul_rn(v1.w, v1.w);
#define ZROW(i) { float4 a = xr[2*(i)], b = xr[2*(i)+1]; \
    r0 = __fadd_rn(r0, __fmul_rn(a.x, a.x)); \
    r1 = __fadd_rn(r1, __fmul_rn(a.y, a.y)); \
    r2 = __fadd_rn(r2, __fmul_rn(a.z, a.z)); \
    r3 = __fadd_rn(r3, __fmul_rn(a.w, a.w)); \
    r4 = __fadd_rn(r4, __fmul_rn(b.x, b.x)); \
    r5 = __fadd_rn(r5, __fmul_rn(b.y, b.y)); \
    r6 = __fadd_rn(r6, __fmul_rn(b.z, b.z)); \
    r7 = __fadd_rn(r7, __fmul_rn(b.w, b.w)); }
    ZROW(1) ZROW(2) ZROW(3) ZROW(4) ZROW(5) ZROW(6) ZROW(7)
#undef ZROW
    z2[row] = __fadd_rn(__fadd_rn(__fadd_rn(r0, r1), __fadd_rn(r2, r3)),
                        __fadd_rn(__fadd_rn(r4, r5), __fadd_rn(r6, r7)));
    gmin[row] = 0xFFFFFFFFFFFFFFFFULL;
}

// ---- K3: argmin pass. thread=code; rows streamed via scalar loads ----
__global__ void __launch_bounds__(512, 2) vq_argmin(const float* __restrict__ x,
                                                    char* __restrict__ ws) {
    const float* et  = (const float*)(ws + WS_ET);
    const float* e2v = (const float*)(ws + WS_E2);
    const float* z2v = (const float*)(ws + WS_Z2);
    unsigned long long* gmin = (unsigned long long*)(ws + WS_GMIN);

    const int k = threadIdx.x;        // this thread's code
    const int lane = threadIdx.x & 63;

    // code row -> 16 named float4s (64 VGPRs, literal use only)
    const float4* er = (const float4*)(et + (size_t)k * D);
    const float4 f0 = er[0],  f1 = er[1],  f2 = er[2],  f3 = er[3];
    const float4 f4 = er[4],  f5 = er[5],  f6 = er[6],  f7 = er[7];
    const float4 f8 = er[8],  f9 = er[9],  f10 = er[10], f11 = er[11];
    const float4 f12 = er[12], f13 = er[13], f14 = er[14], f15 = er[15];
    const float e2k = e2v[k];

    const int rowBase = blockIdx.x * 256;
    for (int r = 0; r < 256; ++r) {
        const int row = rowBase + r;
        const float* xr = x + (size_t)row * D;  // wave-uniform -> s_load
        float a = 0.f;
#define CC(q, EV) \
        a = fmaf(xr[4*(q)+0], EV.x, a); \
        a = fmaf(xr[4*(q)+1], EV.y, a); \
        a = fmaf(xr[4*(q)+2], EV.z, a); \
        a = fmaf(xr[4*(q)+3], EV.w, a);
        CC(0, f0) CC(1, f1) CC(2, f2) CC(3, f3)
        CC(4, f4) CC(5, f5) CC(6, f6) CC(7, f7)
        CC(8, f8) CC(9, f9) CC(10, f10) CC(11, f11)
        CC(12, f12) CC(13, f13) CC(14, f14) CC(15, f15)
#undef CC
        float t = __fadd_rn(z2v[row], e2k);   // z2 uniform -> s operand
        float dist = fmaf(-2.0f, a, t);       // == fl(t - 2a), 2a exact

        // wave argmin: fminf tree returns an input bit-exactly
        float wmin = dist;
#pragma unroll
        for (int off = 1; off < 64; off <<= 1)
            wmin = fminf(wmin, __shfl_xor(wmin, off));
        unsigned long long m = __ballot(dist == wmin);
        int lead = __ffsll(m) - 1;            // lowest lane = lowest k in wave
        if (lane == lead) {
            unsigned long long p =
                ((unsigned long long)__float_as_uint(dist) << 32) |
                (unsigned long long)k;
            atomicMin(&gmin[row], p);         // (dist,k) lexicographic min
        }
    }
}

// ---- K4: gather winning code, write out = fl(x + fl(q-x)), loss partials ----
__global__ void __launch_bounds__(256) vq_gather(const float* __restrict__ x,
                                                 float* __restrict__ out, char* ws) {
    const float* et = (const float*)(ws + WS_ET);
    const unsigned long long* gmin = (const unsigned long long*)(ws + WS_GMIN);
    double* partials = (double*)(ws + WS_PARTIALS);

    const int row = blockIdx.x * 256 + threadIdx.x;
    const int kb = (int)(gmin[row] & 0xFFFFFFFFULL);

    const float4* cq = (const float4*)(et + (size_t)kb * D);
    const float4* xr = (const float4*)(x + (size_t)row * D);
    float4* outr = (float4*)(out + (size_t)row * D);
    double rs = 0.0;
#define OUTQ(g) { \
        float4 e4 = cq[g]; float4 xv = xr[g]; float4 o; \
        float d0 = __fsub_rn(e4.x, xv.x); \
        float d1 = __fsub_rn(e4.y, xv.y); \
        float d2 = __fsub_rn(e4.z, xv.z); \
        float d3 = __fsub_rn(e4.w, xv.w); \
        o.x = __fadd_rn(xv.x, d0); \
        o.y = __fadd_rn(xv.y, d1); \
        o.z = __fadd_rn(xv.z, d2); \
        o.w = __fadd_rn(xv.w, d3); \
        outr[g] = o; \
        rs += (double)__fmul_rn(d0, d0) + (double)__fmul_rn(d1, d1) + \
              (double)__fmul_rn(d2, d2) + (double)__fmul_rn(d3, d3); }
    OUTQ(0) OUTQ(1) OUTQ(2) OUTQ(3) OUTQ(4) OUTQ(5) OUTQ(6) OUTQ(7)
    OUTQ(8) OUTQ(9) OUTQ(10) OUTQ(11) OUTQ(12) OUTQ(13) OUTQ(14) OUTQ(15)
#undef OUTQ

    __shared__ double red[256];
    red[threadIdx.x] = rs;
    __syncthreads();
    for (int s = 128; s > 0; s >>= 1) {
        if (threadIdx.x < s) red[threadIdx.x] += red[threadIdx.x + s];
        __syncthreads();
    }
    if (threadIdx.x == 0) partials[blockIdx.x] = red[0];
}

// ---- K5: finalize loss ----
__global__ void __launch_bounds__(256) vq_finalize(float* __restrict__ out, char* ws) {
    const double* partials = (const double*)(ws + WS_PARTIALS);
    __shared__ double red[256];
    double s = partials[threadIdx.x] + partials[threadIdx.x + 256] +
               partials[threadIdx.x + 512] + partials[threadIdx.x + 768];
    red[threadIdx.x] = s;
    __syncthreads();
    for (int st = 128; st > 0; st >>= 1) {
        if (threadIdx.x < st) red[threadIdx.x] += red[threadIdx.x + st];
        __syncthreads();
    }
    if (threadIdx.x == 0) {
        out[16777216] = (float)(1.25 * red[0] / 16777216.0);
    }
}

extern "C" void kernel_launch(void* const* d_in, const int* in_sizes, int n_in,
                              void* d_out, int out_size, void* d_ws, size_t ws_size,
                              hipStream_t stream) {
    const float* x   = (const float*)d_in[0];
    const float* emb = (const float*)d_in[1];
    float* out = (float*)d_out;
    char* ws = (char*)d_ws;

    vq_prep<<<1, 512, 0, stream>>>(emb, ws);
    vq_z2<<<NROWS / 256, 256, 0, stream>>>(x, ws);
    vq_argmin<<<NROWS / 256, 512, 0, stream>>>(x, ws);
    vq_gather<<<NROWS / 256, 256, 0, stream>>>(x, out, ws);
    vq_finalize<<<1, 256, 0, stream>>>(out, ws);
}

// Round 6
// 248.741 us; speedup vs baseline: 1.9569x; 1.9569x over previous
//
#include <hip/hip_runtime.h>

// VectorQuantizer: MFMA bf16 candidate filter + bit-exact numpy recheck.
// x [64,64,64,64] f32 -> flat [N=262144, D=64]; emb [D=64, K=512].
// out = concat(quantized_st flat [16777216], loss [1]) as f32.
//
// Exact numpy semantics (proven absmax 0.0 in R2/R5) applied to ~1.7
// candidates/row instead of all 512 codes:
//   dist = fl(fl(z2 + e2[k]) - 2*dot), dot = sequential fmaf d=0..63,
//   z2 = np pairwise_sum, e2 = sequential d-ascending, argmin strict-<
//   first-occurrence via u64 atomicMin((distbits<<32)|k)  [dist > 0].
// Candidates from bf16 MFMA approx t_k = e2[k] - 2*dot_bf (z2 cancels
// per-row): |t_bf - t_np| <= ~0.02 worst-row << MARGIN/2 = 0.045 ->
// {t <= rowmin + MARGIN} provably contains the true argmin.
//
// xb (x as bf16, 33.5 MB) lives in d_out[0 .. 33.5MB): vq_cand only READS
// it; vq_gather (separate later kernel) overwrites all of d_out. No overlap.
//
// ws layout (bytes):
//   0       : float  et[512*64]    131072   (f32 codebook, code-major)
//   131072  : float  e2[512]         2048   (np-order norms, exact)
//   133120  : u16    ebT[512*64]    65536   (bf16 codebook, code-major)
//   198656  : float  z2[262144]   1048576   (np pairwise row norms)
//   1247232 : u64    gmin[262144] 2097152   (packed (distbits,k) argmin)
//   3344384 : double partials[1024]  8192   (loss partials)

#define NROWS 262144
#define D 64
#define K 512
#define MARGIN 0.09f
#define INF32 3.4e38f

#define WS_ET 0
#define WS_E2 131072
#define WS_EBT 133120
#define WS_Z2 198656
#define WS_GMIN 1247232
#define WS_PARTIALS 3344384

typedef __attribute__((ext_vector_type(8))) short bf16x8;
typedef __attribute__((ext_vector_type(4))) float f32x4;

__device__ inline unsigned short f2bf(float f) {  // RTNE, finite inputs
    unsigned u = __float_as_uint(f);
    u += 0x7fffu + ((u >> 16) & 1u);
    return (unsigned short)(u >> 16);
}
__device__ inline unsigned pack_bf2(float lo, float hi) {
    unsigned ulo = __float_as_uint(lo); ulo += 0x7fffu + ((ulo >> 16) & 1u);
    unsigned uhi = __float_as_uint(hi); uhi += 0x7fffu + ((uhi >> 16) & 1u);
    return (ulo >> 16) | (uhi & 0xffff0000u);
}

// ---- K1: codebook: f32 transpose + exact np-order norms + bf16 copy ----
__global__ void __launch_bounds__(512) vq_prep(const float* __restrict__ emb, char* ws) {
    float* e2 = (float*)(ws + WS_E2);
    float* et = (float*)(ws + WS_ET);
    unsigned short* ebT = (unsigned short*)(ws + WS_EBT);
    int k = threadIdx.x;
    float v0 = emb[k];
    et[k * D] = v0;
    ebT[k * D] = f2bf(v0);
    float s = __fmul_rn(v0, v0);
    for (int d = 1; d < D; ++d) {
        float v = emb[d * K + k];
        et[k * D + d] = v;
        ebT[k * D + d] = f2bf(v);
        s = __fadd_rn(s, __fmul_rn(v, v));  // sequential d (np axis-0 reduce)
    }
    e2[k] = s;
}

// ---- K2: z2 (np pairwise) + x->bf16 into d_out scratch + gmin init ----
__global__ void __launch_bounds__(256) vq_z2x(const float* __restrict__ x,
                                              unsigned* __restrict__ xbu, char* ws) {
    float* z2 = (float*)(ws + WS_Z2);
    unsigned long long* gmin = (unsigned long long*)(ws + WS_GMIN);
    const int row = blockIdx.x * 256 + threadIdx.x;
    const float4* xr = (const float4*)(x + (size_t)row * D);
    uint2* xbr = (uint2*)(xbu + (size_t)row * 32);

    float4 a0 = xr[0], b0 = xr[1];
    float r0 = __fmul_rn(a0.x, a0.x), r1 = __fmul_rn(a0.y, a0.y);
    float r2 = __fmul_rn(a0.z, a0.z), r3 = __fmul_rn(a0.w, a0.w);
    float r4 = __fmul_rn(b0.x, b0.x), r5 = __fmul_rn(b0.y, b0.y);
    float r6 = __fmul_rn(b0.z, b0.z), r7 = __fmul_rn(b0.w, b0.w);
    xbr[0] = make_uint2(pack_bf2(a0.x, a0.y), pack_bf2(a0.z, a0.w));
    xbr[1] = make_uint2(pack_bf2(b0.x, b0.y), pack_bf2(b0.z, b0.w));
#define ZR(g) { float4 a = xr[2*(g)], b = xr[2*(g)+1]; \
    r0 = __fadd_rn(r0, __fmul_rn(a.x, a.x)); \
    r1 = __fadd_rn(r1, __fmul_rn(a.y, a.y)); \
    r2 = __fadd_rn(r2, __fmul_rn(a.z, a.z)); \
    r3 = __fadd_rn(r3, __fmul_rn(a.w, a.w)); \
    r4 = __fadd_rn(r4, __fmul_rn(b.x, b.x)); \
    r5 = __fadd_rn(r5, __fmul_rn(b.y, b.y)); \
    r6 = __fadd_rn(r6, __fmul_rn(b.z, b.z)); \
    r7 = __fadd_rn(r7, __fmul_rn(b.w, b.w)); \
    xbr[2*(g)]   = make_uint2(pack_bf2(a.x, a.y), pack_bf2(a.z, a.w)); \
    xbr[2*(g)+1] = make_uint2(pack_bf2(b.x, b.y), pack_bf2(b.z, b.w)); }
    ZR(1) ZR(2) ZR(3) ZR(4) ZR(5) ZR(6) ZR(7)
#undef ZR
    z2[row] = __fadd_rn(__fadd_rn(__fadd_rn(r0, r1), __fadd_rn(r2, r3)),
                        __fadd_rn(__fadd_rn(r4, r5), __fadd_rn(r6, r7)));
    gmin[row] = 0xFFFFFFFFFFFFFFFFULL;
}

// ---- K3: MFMA sweep1 (row mins) + sweep2 (candidates) + exact recheck ----
__global__ void __launch_bounds__(256) vq_cand(const float* __restrict__ x,
                                               const unsigned short* __restrict__ xb,
                                               char* ws) {
    const float* et  = (const float*)(ws + WS_ET);
    const float* e2f = (const float*)(ws + WS_E2);
    const unsigned short* ebT = (const unsigned short*)(ws + WS_EBT);
    const float* z2v = (const float*)(ws + WS_Z2);
    unsigned long long* gmin = (unsigned long long*)(ws + WS_GMIN);

    __shared__ int ccnt;
    __shared__ unsigned cl[4096];

    const int tid = threadIdx.x;
    const int wv = tid >> 6, lane = tid & 63;
    const int c15 = lane & 15;            // A-row / B-col / C-col
    const int kofs = (lane >> 4) * 8;     // k offset within frag
    const int gr4 = (lane >> 4) * 4;      // C row base for this lane
    const int rowBase = blockIdx.x * 256 + wv * 64;

    if (tid == 0) ccnt = 0;
    __syncthreads();

    float m00 = INF32, m01 = INF32, m02 = INF32, m03 = INF32;
    float m10 = INF32, m11 = INF32, m12 = INF32, m13 = INF32;
    float m20 = INF32, m21 = INF32, m22 = INF32, m23 = INF32;
    float m30 = INF32, m31 = INF32, m32 = INF32, m33 = INF32;

#define RT_MIN(rt, M0, M1, M2, M3) { \
    const unsigned short* ap = xb + (((size_t)(rowBase + (rt)*16 + c15)) << 6) + kofs; \
    bf16x8 a0 = *(const bf16x8*)ap; \
    bf16x8 a1 = *(const bf16x8*)(ap + 32); \
    f32x4 acc = {0.f, 0.f, 0.f, 0.f}; \
    acc = __builtin_amdgcn_mfma_f32_16x16x32_bf16(a0, bb0, acc, 0, 0, 0); \
    acc = __builtin_amdgcn_mfma_f32_16x16x32_bf16(a1, bb1, acc, 0, 0, 0); \
    M0 = fminf(M0, e2c - 2.0f * acc[0]); \
    M1 = fminf(M1, e2c - 2.0f * acc[1]); \
    M2 = fminf(M2, e2c - 2.0f * acc[2]); \
    M3 = fminf(M3, e2c - 2.0f * acc[3]); }

    for (int j = 0; j < 32; ++j) {
        const unsigned short* bp = ebT + (((size_t)(j * 16 + c15)) << 6) + kofs;
        bf16x8 bb0 = *(const bf16x8*)bp;
        bf16x8 bb1 = *(const bf16x8*)(bp + 32);
        float e2c = e2f[j * 16 + c15];
        RT_MIN(0, m00, m01, m02, m03)
        RT_MIN(1, m10, m11, m12, m13)
        RT_MIN(2, m20, m21, m22, m23)
        RT_MIN(3, m30, m31, m32, m33)
    }
#undef RT_MIN

    // min across the 16 lanes (cols) of each lane-group, then add margin
#define RED(v) v = fminf(v, __shfl_xor(v, 1)); v = fminf(v, __shfl_xor(v, 2)); \
               v = fminf(v, __shfl_xor(v, 4)); v = fminf(v, __shfl_xor(v, 8)); \
               v += MARGIN;
    RED(m00) RED(m01) RED(m02) RED(m03)
    RED(m10) RED(m11) RED(m12) RED(m13)
    RED(m20) RED(m21) RED(m22) RED(m23)
    RED(m30) RED(m31) RED(m32) RED(m33)
#undef RED

#define PUSH(rt, r) { int idx = atomicAdd(&ccnt, 1); if (idx < 4096) \
    cl[idx] = ((unsigned)(wv * 64 + (rt) * 16 + gr4 + (r)) << 16) | \
              (unsigned)(j * 16 + c15); }
#define RT_CAND(rt, M0, M1, M2, M3) { \
    const unsigned short* ap = xb + (((size_t)(rowBase + (rt)*16 + c15)) << 6) + kofs; \
    bf16x8 a0 = *(const bf16x8*)ap; \
    bf16x8 a1 = *(const bf16x8*)(ap + 32); \
    f32x4 acc = {0.f, 0.f, 0.f, 0.f}; \
    acc = __builtin_amdgcn_mfma_f32_16x16x32_bf16(a0, bb0, acc, 0, 0, 0); \
    acc = __builtin_amdgcn_mfma_f32_16x16x32_bf16(a1, bb1, acc, 0, 0, 0); \
    if (e2c - 2.0f * acc[0] <= M0) PUSH(rt, 0) \
    if (e2c - 2.0f * acc[1] <= M1) PUSH(rt, 1) \
    if (e2c - 2.0f * acc[2] <= M2) PUSH(rt, 2) \
    if (e2c - 2.0f * acc[3] <= M3) PUSH(rt, 3) }

    for (int j = 0; j < 32; ++j) {
        const unsigned short* bp = ebT + (((size_t)(j * 16 + c15)) << 6) + kofs;
        bf16x8 bb0 = *(const bf16x8*)bp;
        bf16x8 bb1 = *(const bf16x8*)(bp + 32);
        float e2c = e2f[j * 16 + c15];
        RT_CAND(0, m00, m01, m02, m03)
        RT_CAND(1, m10, m11, m12, m13)
        RT_CAND(2, m20, m21, m22, m23)
        RT_CAND(3, m30, m31, m32, m33)
    }
#undef RT_CAND
#undef PUSH

    __syncthreads();
    const int cnt = min(ccnt, 4096);
    const int blockRow0 = blockIdx.x * 256;
    for (int i = tid; i < cnt; i += 256) {
        unsigned e = cl[i];
        int row = blockRow0 + (int)(e >> 16);
        int k = (int)(e & 0x1ffu);
        const float* xr = x + (size_t)row * D;
        const float* ep = et + (size_t)k * D;
        float a = 0.f;
#pragma unroll
        for (int d = 0; d < D; ++d) a = fmaf(xr[d], ep[d], a);  // exact np chain
        float dist = __fsub_rn(__fadd_rn(z2v[row], e2f[k]), __fmul_rn(2.0f, a));
        unsigned long long p =
            ((unsigned long long)__float_as_uint(dist) << 32) | (unsigned)k;
        atomicMin(&gmin[row], p);
    }
}

// ---- K4: gather winning code, out = fl(x + fl(q-x)), loss partials ----
__global__ void __launch_bounds__(256) vq_gather(const float* __restrict__ x,
                                                 float* __restrict__ out, char* ws) {
    const float* et = (const float*)(ws + WS_ET);
    const unsigned long long* gmin = (const unsigned long long*)(ws + WS_GMIN);
    double* partials = (double*)(ws + WS_PARTIALS);

    const int row = blockIdx.x * 256 + threadIdx.x;
    const int kb = (int)(gmin[row] & 0xFFFFFFFFULL);

    const float4* cq = (const float4*)(et + (size_t)kb * D);
    const float4* xr = (const float4*)(x + (size_t)row * D);
    float4* outr = (float4*)(out + (size_t)row * D);
    double rs = 0.0;
#define OUTQ(g) { \
        float4 e4 = cq[g]; float4 xv = xr[g]; float4 o; \
        float d0 = __fsub_rn(e4.x, xv.x); \
        float d1 = __fsub_rn(e4.y, xv.y); \
        float d2 = __fsub_rn(e4.z, xv.z); \
        float d3 = __fsub_rn(e4.w, xv.w); \
        o.x = __fadd_rn(xv.x, d0); \
        o.y = __fadd_rn(xv.y, d1); \
        o.z = __fadd_rn(xv.z, d2); \
        o.w = __fadd_rn(xv.w, d3); \
        outr[g] = o; \
        rs += (double)__fmul_rn(d0, d0) + (double)__fmul_rn(d1, d1) + \
              (double)__fmul_rn(d2, d2) + (double)__fmul_rn(d3, d3); }
    OUTQ(0) OUTQ(1) OUTQ(2) OUTQ(3) OUTQ(4) OUTQ(5) OUTQ(6) OUTQ(7)
    OUTQ(8) OUTQ(9) OUTQ(10) OUTQ(11) OUTQ(12) OUTQ(13) OUTQ(14) OUTQ(15)
#undef OUTQ

    __shared__ double red[256];
    red[threadIdx.x] = rs;
    __syncthreads();
    for (int s = 128; s > 0; s >>= 1) {
        if (threadIdx.x < s) red[threadIdx.x] += red[threadIdx.x + s];
        __syncthreads();
    }
    if (threadIdx.x == 0) partials[blockIdx.x] = red[0];
}

// ---- K5: finalize loss ----
__global__ void __launch_bounds__(256) vq_finalize(float* __restrict__ out, char* ws) {
    const double* partials = (const double*)(ws + WS_PARTIALS);
    __shared__ double red[256];
    double s = partials[threadIdx.x] + partials[threadIdx.x + 256] +
               partials[threadIdx.x + 512] + partials[threadIdx.x + 768];
    red[threadIdx.x] = s;
    __syncthreads();
    for (int st = 128; st > 0; st >>= 1) {
        if (threadIdx.x < st) red[threadIdx.x] += red[threadIdx.x + st];
        __syncthreads();
    }
    if (threadIdx.x == 0) {
        out[16777216] = (float)(1.25 * red[0] / 16777216.0);
    }
}

extern "C" void kernel_launch(void* const* d_in, const int* in_sizes, int n_in,
                              void* d_out, int out_size, void* d_ws, size_t ws_size,
                              hipStream_t stream) {
    const float* x   = (const float*)d_in[0];
    const float* emb = (const float*)d_in[1];
    float* out = (float*)d_out;
    char* ws = (char*)d_ws;

    vq_prep<<<1, 512, 0, stream>>>(emb, ws);
    vq_z2x<<<NROWS / 256, 256, 0, stream>>>(x, (unsigned*)d_out, ws);
    vq_cand<<<NROWS / 256, 256, 0, stream>>>(x, (const unsigned short*)d_out, ws);
    vq_gather<<<NROWS / 256, 256, 0, stream>>>(x, out, ws);
    vq_finalize<<<1, 256, 0, stream>>>(out, ws);
}

// Round 7
// 183.714 us; speedup vs baseline: 2.6496x; 1.3540x over previous
//
#include <hip/hip_runtime.h>

// VectorQuantizer: fused MFMA bf16 filter + bit-exact numpy recheck + gather.
// x [64,64,64,64] f32 -> flat [N=262144, D=64]; emb [D=64, K=512].
// out = concat(quantized_st flat [16777216], loss [1]) as f32.
//
// One block = 256 rows. Pipeline inside vq_fused:
//   stage half-codebook (bf16, XOR-swizzled) in LDS -> MFMA sweep1 (row mins)
//   -> re-stage -> MFMA sweep2 (candidates: t <= rowmin + MARGIN)
//   -> exact np recheck of candidates (u64 atomicMin in LDS, block-private)
//   -> gather + out = fl(x + fl(q-x)) + fp64 loss partial.
// Exact numpy semantics (proven absmax 0.0 in R2/R5/R6) on candidates only:
//   dist = fl(fl(z2+e2[k]) - 2*dot), dot = sequential fmaf d=0..63,
//   z2 = np pairwise_sum, e2 = sequential d-ascending, argmin strict-<
//   first-occurrence == lexicographic u64 min of (distbits<<32)|k [dist>0].
// MARGIN=0.09 >> 2*max bf16-vs-np t-error (~0.04) -> true argmin always in
// candidate set (empirically validated in R6, same bf16 arithmetic).
//
// ws layout (bytes):
//   0      : float  et[512*64]    131072  (f32 codebook, code-major)
//   131072 : float  e2[512]         2048  (np-order norms, exact)
//   133120 : u16    ebT[512*64]    65536  (bf16 codebook, code-major)
//   198656 : double partials[1024]  8192  (loss partials)

#define NROWS 262144
#define D 64
#define K 512
#define MARGIN 0.09f
#define INF32 3.4e38f

#define WS_ET 0
#define WS_E2 131072
#define WS_EBT 133120
#define WS_PARTIALS 198656

typedef __attribute__((ext_vector_type(8))) short bf16x8;
typedef __attribute__((ext_vector_type(4))) float f32x4;

union ClRed { unsigned cl[2048]; double red[256]; };

__device__ inline unsigned short f2bf(float f) {  // RTNE, finite inputs
    unsigned u = __float_as_uint(f);
    u += 0x7fffu + ((u >> 16) & 1u);
    return (unsigned short)(u >> 16);
}
__device__ inline unsigned pack_bf2(float lo, float hi) {
    unsigned ulo = __float_as_uint(lo); ulo += 0x7fffu + ((ulo >> 16) & 1u);
    unsigned uhi = __float_as_uint(hi); uhi += 0x7fffu + ((uhi >> 16) & 1u);
    return (ulo >> 16) | (uhi & 0xffff0000u);
}
__device__ inline bf16x8 pack8(float4 p, float4 q) {
    union { unsigned u[4]; bf16x8 v; } r;
    r.u[0] = pack_bf2(p.x, p.y); r.u[1] = pack_bf2(p.z, p.w);
    r.u[2] = pack_bf2(q.x, q.y); r.u[3] = pack_bf2(q.z, q.w);
    return r.v;
}

// ---- K1: codebook prep (8 blocks x 64 threads, one code per thread) ----
__global__ void __launch_bounds__(64) vq_prep(const float* __restrict__ emb, char* ws) {
    float* e2 = (float*)(ws + WS_E2);
    float* et = (float*)(ws + WS_ET);
    unsigned short* ebT = (unsigned short*)(ws + WS_EBT);
    int k = blockIdx.x * 64 + threadIdx.x;
    float v0 = emb[k];
    et[k * D] = v0;
    ebT[k * D] = f2bf(v0);
    float s = __fmul_rn(v0, v0);
    for (int d = 1; d < D; ++d) {
        float v = emb[d * K + k];
        et[k * D + d] = v;
        ebT[k * D + d] = f2bf(v);
        s = __fadd_rn(s, __fmul_rn(v, v));  // sequential d (np axis-0 reduce)
    }
    e2[k] = s;
}

// ---- exact np-order dist for one (row, k), packed (distbits<<32)|k ----
__device__ __noinline__ unsigned long long exact_pack(
        const float* __restrict__ x, const float* __restrict__ et,
        const float* __restrict__ e2f, int row, int k) {
    const float* xr = x + (size_t)row * D;
    float r0 = __fmul_rn(xr[0], xr[0]), r1 = __fmul_rn(xr[1], xr[1]);
    float r2 = __fmul_rn(xr[2], xr[2]), r3 = __fmul_rn(xr[3], xr[3]);
    float r4 = __fmul_rn(xr[4], xr[4]), r5 = __fmul_rn(xr[5], xr[5]);
    float r6 = __fmul_rn(xr[6], xr[6]), r7 = __fmul_rn(xr[7], xr[7]);
    for (int i = 8; i < 64; i += 8) {
        r0 = __fadd_rn(r0, __fmul_rn(xr[i],     xr[i]));
        r1 = __fadd_rn(r1, __fmul_rn(xr[i + 1], xr[i + 1]));
        r2 = __fadd_rn(r2, __fmul_rn(xr[i + 2], xr[i + 2]));
        r3 = __fadd_rn(r3, __fmul_rn(xr[i + 3], xr[i + 3]));
        r4 = __fadd_rn(r4, __fmul_rn(xr[i + 4], xr[i + 4]));
        r5 = __fadd_rn(r5, __fmul_rn(xr[i + 5], xr[i + 5]));
        r6 = __fadd_rn(r6, __fmul_rn(xr[i + 6], xr[i + 6]));
        r7 = __fadd_rn(r7, __fmul_rn(xr[i + 7], xr[i + 7]));
    }
    float z2 = __fadd_rn(__fadd_rn(__fadd_rn(r0, r1), __fadd_rn(r2, r3)),
                         __fadd_rn(__fadd_rn(r4, r5), __fadd_rn(r6, r7)));
    const float* ep = et + (size_t)k * D;
    float a = 0.f;
    for (int d = 0; d < D; ++d) a = fmaf(xr[d], ep[d], a);  // sequential np chain
    float dist = __fsub_rn(__fadd_rn(z2, e2f[k]), __fmul_rn(2.0f, a));
    return ((unsigned long long)__float_as_uint(dist) << 32) | (unsigned)k;
}

// ---- K2: fused filter + recheck + gather ----
__global__ void __launch_bounds__(256) vq_fused(const float* __restrict__ x,
                                                float* __restrict__ out,
                                                char* __restrict__ ws) {
    const float* et  = (const float*)(ws + WS_ET);
    const float* e2f = (const float*)(ws + WS_E2);
    const unsigned short* ebT = (const unsigned short*)(ws + WS_EBT);
    double* partials = (double*)(ws + WS_PARTIALS);

    __shared__ unsigned short ebs[16384];          // 32KB: half codebook, swizzled
    __shared__ float le2[512];
    __shared__ unsigned long long lgmin[256];      // block-private argmin
    __shared__ int ccnt;
    __shared__ ClRed u;

    const int tid = threadIdx.x;
    const int wv = tid >> 6, lane = tid & 63;
    const int c15 = lane & 15;
    const int g = lane >> 4;
    const int kofs = g * 8;
    const int gr4 = g * 4;
    const int blockRow0 = blockIdx.x * 256;
    const int rowBase = blockRow0 + wv * 64;

    lgmin[tid] = 0xFFFFFFFFFFFFFFFFULL;
    if (tid == 0) ccnt = 0;
    le2[tid] = e2f[tid];
    le2[tid + 256] = e2f[tid + 256];

    // hoist A: convert own x rows to bf16 fragments in registers (once)
    bf16x8 aA0, aA1, aB0, aB1, aC0, aC1, aD0, aD1;
#define LOADA(RT, A0, A1) { \
    const float* xp = x + ((size_t)(rowBase + (RT) * 16 + c15)) * D + kofs; \
    float4 p0 = *(const float4*)xp; \
    float4 p1 = *(const float4*)(xp + 4); \
    float4 p2 = *(const float4*)(xp + 32); \
    float4 p3 = *(const float4*)(xp + 36); \
    A0 = pack8(p0, p1); A1 = pack8(p2, p3); }
    LOADA(0, aA0, aA1) LOADA(1, aB0, aB1) LOADA(2, aC0, aC1) LOADA(3, aD0, aD1)
#undef LOADA

    // stage half h of the bf16 codebook into LDS, XOR-swizzled (slot ^= k&7)
#define STAGE(h) { \
    const uint4* src = (const uint4*)(ebT + (size_t)(h) * 16384); \
    _Pragma("unroll") \
    for (int i = 0; i < 8; ++i) { \
        int c = i * 256 + tid; \
        int kl = c >> 3, s = c & 7; \
        uint4 v = src[c]; \
        *(uint4*)(ebs + kl * 64 + ((s ^ (kl & 7)) * 8)) = v; \
    } }

#define SW1(A0, A1, M0, M1, M2, M3) { \
    f32x4 acc = {0.f, 0.f, 0.f, 0.f}; \
    acc = __builtin_amdgcn_mfma_f32_16x16x32_bf16(A0, bb0, acc, 0, 0, 0); \
    acc = __builtin_amdgcn_mfma_f32_16x16x32_bf16(A1, bb1, acc, 0, 0, 0); \
    M0 = fminf(M0, e2c - 2.0f * acc[0]); \
    M1 = fminf(M1, e2c - 2.0f * acc[1]); \
    M2 = fminf(M2, e2c - 2.0f * acc[2]); \
    M3 = fminf(M3, e2c - 2.0f * acc[3]); }

    float m00 = INF32, m01 = INF32, m02 = INF32, m03 = INF32;
    float m10 = INF32, m11 = INF32, m12 = INF32, m13 = INF32;
    float m20 = INF32, m21 = INF32, m22 = INF32, m23 = INF32;
    float m30 = INF32, m31 = INF32, m32 = INF32, m33 = INF32;

    for (int h = 0; h < 2; ++h) {
        __syncthreads();
        STAGE(h)
        __syncthreads();
        for (int j = 0; j < 16; ++j) {
            const int kkl = j * 16 + c15;
            bf16x8 bb0 = *(const bf16x8*)(ebs + kkl * 64 + ((g ^ (kkl & 7)) * 8));
            bf16x8 bb1 = *(const bf16x8*)(ebs + kkl * 64 + (((g + 4) ^ (kkl & 7)) * 8));
            float e2c = le2[h * 256 + kkl];
            SW1(aA0, aA1, m00, m01, m02, m03)
            SW1(aB0, aB1, m10, m11, m12, m13)
            SW1(aC0, aC1, m20, m21, m22, m23)
            SW1(aD0, aD1, m30, m31, m32, m33)
        }
    }
#undef SW1

    // min across the 16 lanes (cols) of each lane-group, then add margin
#define RED(v) v = fminf(v, __shfl_xor(v, 1)); v = fminf(v, __shfl_xor(v, 2)); \
               v = fminf(v, __shfl_xor(v, 4)); v = fminf(v, __shfl_xor(v, 8)); \
               v += MARGIN;
    RED(m00) RED(m01) RED(m02) RED(m03)
    RED(m10) RED(m11) RED(m12) RED(m13)
    RED(m20) RED(m21) RED(m22) RED(m23)
    RED(m30) RED(m31) RED(m32) RED(m33)
#undef RED

#define PUSH(RT, R) { int idx = atomicAdd(&ccnt, 1); \
    if (idx < 2048) u.cl[idx] = \
        ((unsigned)(wv * 64 + (RT) * 16 + gr4 + (R)) << 16) | (unsigned)kg; \
    else atomicMin(&lgmin[wv * 64 + (RT) * 16 + gr4 + (R)], \
        exact_pack(x, et, e2f, blockRow0 + wv * 64 + (RT) * 16 + gr4 + (R), kg)); }

#define SW2(RT, A0, A1, M0, M1, M2, M3) { \
    f32x4 acc = {0.f, 0.f, 0.f, 0.f}; \
    acc = __builtin_amdgcn_mfma_f32_16x16x32_bf16(A0, bb0, acc, 0, 0, 0); \
    acc = __builtin_amdgcn_mfma_f32_16x16x32_bf16(A1, bb1, acc, 0, 0, 0); \
    if (e2c - 2.0f * acc[0] <= M0) PUSH(RT, 0) \
    if (e2c - 2.0f * acc[1] <= M1) PUSH(RT, 1) \
    if (e2c - 2.0f * acc[2] <= M2) PUSH(RT, 2) \
    if (e2c - 2.0f * acc[3] <= M3) PUSH(RT, 3) }

    for (int h = 0; h < 2; ++h) {
        __syncthreads();
        STAGE(h)
        __syncthreads();
        for (int j = 0; j < 16; ++j) {
            const int kkl = j * 16 + c15;
            const int kg = h * 256 + kkl;
            bf16x8 bb0 = *(const bf16x8*)(ebs + kkl * 64 + ((g ^ (kkl & 7)) * 8));
            bf16x8 bb1 = *(const bf16x8*)(ebs + kkl * 64 + (((g + 4) ^ (kkl & 7)) * 8));
            float e2c = le2[kg];
            SW2(0, aA0, aA1, m00, m01, m02, m03)
            SW2(1, aB0, aB1, m10, m11, m12, m13)
            SW2(2, aC0, aC1, m20, m21, m22, m23)
            SW2(3, aD0, aD1, m30, m31, m32, m33)
        }
    }
#undef SW2
#undef PUSH
#undef STAGE

    __syncthreads();
    // exact recheck of listed candidates (block-private rows -> LDS atomicMin)
    const int cnt = (ccnt < 2048) ? ccnt : 2048;
    for (int i = tid; i < cnt; i += 256) {
        unsigned e = u.cl[i];
        int rowLocal = (int)(e >> 16);
        int k = (int)(e & 0x1ffu);
        atomicMin(&lgmin[rowLocal], exact_pack(x, et, e2f, blockRow0 + rowLocal, k));
    }
    __syncthreads();

    // gather winning code; out = fl(x + fl(q - x)); fp64 loss partial
    const int row = blockRow0 + tid;
    const int kb = (int)(lgmin[tid] & 0xFFFFFFFFULL);
    const float4* cq = (const float4*)(et + (size_t)kb * D);
    const float4* xr = (const float4*)(x + (size_t)row * D);
    float4* outr = (float4*)(out + (size_t)row * D);
    double rs = 0.0;
#define OUTQ(G) { \
        float4 e4 = cq[G]; float4 xv = xr[G]; float4 o; \
        float d0 = __fsub_rn(e4.x, xv.x); \
        float d1 = __fsub_rn(e4.y, xv.y); \
        float d2 = __fsub_rn(e4.z, xv.z); \
        float d3 = __fsub_rn(e4.w, xv.w); \
        o.x = __fadd_rn(xv.x, d0); \
        o.y = __fadd_rn(xv.y, d1); \
        o.z = __fadd_rn(xv.z, d2); \
        o.w = __fadd_rn(xv.w, d3); \
        outr[G] = o; \
        rs += (double)__fmul_rn(d0, d0) + (double)__fmul_rn(d1, d1) + \
              (double)__fmul_rn(d2, d2) + (double)__fmul_rn(d3, d3); }
    OUTQ(0) OUTQ(1) OUTQ(2) OUTQ(3) OUTQ(4) OUTQ(5) OUTQ(6) OUTQ(7)
    OUTQ(8) OUTQ(9) OUTQ(10) OUTQ(11) OUTQ(12) OUTQ(13) OUTQ(14) OUTQ(15)
#undef OUTQ

    u.red[tid] = rs;   // safe: cl reads finished before the last barrier
    __syncthreads();
    for (int s = 128; s > 0; s >>= 1) {
        if (tid < s) u.red[tid] += u.red[tid + s];
        __syncthreads();
    }
    if (tid == 0) partials[blockIdx.x] = u.red[0];
}

// ---- K3: finalize loss ----
__global__ void __launch_bounds__(256) vq_finalize(float* __restrict__ out, char* ws) {
    const double* partials = (const double*)(ws + WS_PARTIALS);
    __shared__ double red[256];
    double s = partials[threadIdx.x] + partials[threadIdx.x + 256] +
               partials[threadIdx.x + 512] + partials[threadIdx.x + 768];
    red[threadIdx.x] = s;
    __syncthreads();
    for (int st = 128; st > 0; st >>= 1) {
        if (threadIdx.x < st) red[threadIdx.x] += red[threadIdx.x + st];
        __syncthreads();
    }
    if (threadIdx.x == 0) {
        out[16777216] = (float)(1.25 * red[0] / 16777216.0);
    }
}

extern "C" void kernel_launch(void* const* d_in, const int* in_sizes, int n_in,
                              void* d_out, int out_size, void* d_ws, size_t ws_size,
                              hipStream_t stream) {
    const float* x   = (const float*)d_in[0];
    const float* emb = (const float*)d_in[1];
    float* out = (float*)d_out;
    char* ws = (char*)d_ws;

    vq_prep<<<8, 64, 0, stream>>>(emb, ws);
    vq_fused<<<NROWS / 256, 256, 0, stream>>>(x, out, ws);
    vq_finalize<<<1, 256, 0, stream>>>(out, ws);
}